// Round 7
// baseline (325.561 us; speedup 1.0000x reference)
//
#include <hip/hip_runtime.h>

typedef _Float16 half8 __attribute__((ext_vector_type(8)));
typedef _Float16 half4 __attribute__((ext_vector_type(4)));
typedef float floatx16 __attribute__((ext_vector_type(16)));

constexpr int Bn = 32768, Kn = 4096, Dn = 256;
constexpr int BM = 128;          // rows per block
constexpr int NI = 64;           // ni steps (64 codes each)
constexpr int NCH = 256;         // chunks; chunk = 64 codes x 64 k x {hi|lo} = 16KB

// ---- prep: exact fp32 ||e||^2 + swizzle-baked f16 hi|lo codebook ----
// w16 layout: [code][kc 0..3][256B row: hi 128B | lo 128B]; each row's 16B
// granules XOR-permuted by (code&15) so main-kernel DMA is a linear row copy.
// (Proven R4/R5: absmax=0, SQ_LDS_BANK_CONFLICT=0.)
__global__ void prep_kernel(const float* __restrict__ w, float* __restrict__ esq,
                            char* __restrict__ w16) {
    int code = blockIdx.x * 4 + (threadIdx.x >> 6);
    int l = threadIdx.x & 63;
    float4 v = *reinterpret_cast<const float4*>(w + (size_t)code * Dn + l * 4);
    float s = v.x * v.x + v.y * v.y + v.z * v.z + v.w * v.w;
    #pragma unroll
    for (int off = 32; off; off >>= 1) s += __shfl_xor(s, off);
    if (l == 0) esq[code] = s;

    float fv[4] = {v.x, v.y, v.z, v.w};
    half4 h, lo;
    #pragma unroll
    for (int j = 0; j < 4; ++j) {
        _Float16 hh = (_Float16)fv[j];
        h[j] = hh;
        lo[j] = (_Float16)(fv[j] - (float)hh);
    }
    const int kc = l >> 4;
    const int o_h = (l & 15) * 8;
    const int swz = (code & 15) << 4;
    char* row = w16 + (size_t)code * 1024 + kc * 256;
    *reinterpret_cast<half4*>(row + (o_h ^ swz)) = h;
    *reinterpret_cast<half4*>(row + ((o_h + 128) ^ swz)) = lo;
}

#define GLDS(gsrc, ldsoff)                                                        \
    __builtin_amdgcn_global_load_lds(                                             \
        (const __attribute__((address_space(1))) unsigned int*)(const void*)(gsrc),\
        (__attribute__((address_space(3))) unsigned int*)(void*)(smem + (ldsoff)), \
        16, 0, 0)

#define MFMA(a, b, c) __builtin_amdgcn_mfma_f32_32x32x16_f16((a), (b), (c), 0, 0, 0)

// 8 waves (4M x 2N), M=32 rows/wave. VGPR-safe (~230), no spill.
// LDS map: bufs 4x16384 [0,65536) | esq_s [65536,81920) | comb [81920,83968) | idxF [83968,84480)
__global__ void
__launch_bounds__(512, 2)
vq_kernel(const float* __restrict__ z, const float* __restrict__ w,
          const float* __restrict__ esq, const char* __restrict__ w16,
          float* __restrict__ out0, float* __restrict__ out1,
          float* __restrict__ out2) {
    __shared__ char smem[84480];
    const int tid = threadIdx.x;
    const int wv = tid >> 6, l = tid & 63;
    const int mw = wv >> 1, nw = wv & 1;       // 4 M-waves (32 rows) x 2 N-halves (32 cols)
    const int lh = l >> 5, ll = l & 31;
    const int blkRow = blockIdx.x * BM;

    // esq -> LDS
    float* esq_s = reinterpret_cast<float*>(smem + 65536);
    #pragma unroll
    for (int j = 0; j < 8; ++j) esq_s[j * 512 + tid] = esq[j * 512 + tid];

    // A: 32 z-rows per wave as f16 hi/lo (128 VGPR). lane: row=ll, k=ks*16+lh*8+j
    half8 a_hi[16], a_lo[16];
    {
        const float* zr = z + (size_t)(blkRow + mw * 32 + ll) * Dn + lh * 8;
        #pragma unroll
        for (int ks = 0; ks < 16; ++ks) {
            float4 f0 = *reinterpret_cast<const float4*>(zr + ks * 16);
            float4 f1 = *reinterpret_cast<const float4*>(zr + ks * 16 + 4);
            float fv[8] = {f0.x, f0.y, f0.z, f0.w, f1.x, f1.y, f1.z, f1.w};
            #pragma unroll
            for (int j = 0; j < 8; ++j) {
                _Float16 h = (_Float16)fv[j];
                a_hi[ks][j] = h;
                a_lo[ks][j] = (_Float16)(fv[j] - (float)h);
            }
        }
    }

    // DMA: wave stages 2KB/chunk as 2 linear 1KB row-copies.
    // granule g = wv*128 + j*64 + l -> src code = wv*8 + j*4 + (l>>4), byte (l&15)*16
    const size_t srcOff0 = (size_t)(wv * 8 + (l >> 4)) * 1024 + (l & 15) * 16;
    const int ldsOff0 = wv * 2048;

    // ds_read addrs (swizzled), col c_loc = nw*32 + ll
    int addrH[4], addrL[4];
    {
        const int c_loc = nw * 32 + ll;
        const int swz = (c_loc & 15) << 4;
        #pragma unroll
        for (int ks = 0; ks < 4; ++ks) {
            const int o = ks * 32 + lh * 16;
            addrH[ks] = c_loc * 256 + (o ^ swz);
            addrL[ks] = c_loc * 256 + ((o + 128) ^ swz);
        }
    }

    float rbv[16];
    unsigned rbn[4] = {0, 0, 0, 0};   // packed winning-ni bytes (4 per reg)
    #pragma unroll
    for (int q = 0; q < 16; ++q) rbv[q] = 3.4e38f;

    asm volatile("s_waitcnt vmcnt(0)" ::: "memory");
    __syncthreads();   // esq + A loads drained; vmcnt base 0

    // prologue: DMA chunks 0,1
    GLDS(w16 + srcOff0, ldsOff0);
    GLDS(w16 + 4096 + srcOff0, ldsOff0 + 1024);
    GLDS(w16 + 256 + srcOff0, 16384 + ldsOff0);
    GLDS(w16 + 256 + 4096 + srcOff0, 16384 + ldsOff0 + 1024);
    asm volatile("s_waitcnt vmcnt(2)" ::: "memory");   // chunk 0 complete (own share)
    __builtin_amdgcn_s_barrier();
    asm volatile("" ::: "memory");

    // frag double-buffer, parity = chunk&1
    half8 sh0[4], sl0[4], sh1[4], sl1[4];
    #pragma unroll
    for (int ks = 0; ks < 4; ++ks) {
        sh0[ks] = *reinterpret_cast<const half8*>(smem + addrH[ks]);
        sl0[ks] = *reinterpret_cast<const half8*>(smem + addrL[ks]);
    }

    for (int ni = 0; ni < NI; ++ni) {
        floatx16 accA = {}, accB = {};   // two chains: hi*hi | hi*lo + lo*hi
        #pragma unroll
        for (int kc = 0; kc < 4; ++kc) {
            const int c = ni * 4 + kc;
            if (c + 2 < NCH) {   // prefetch chunk c+2 -> buf (kc+2)&3 (last read 2 barriers ago)
                const char* s2 = w16 + (size_t)((c + 2) >> 2) * 65536 + ((c + 2) & 3) * 256 + srcOff0;
                const int d2 = (((kc + 2) & 3) * 16384) + ldsOff0;
                GLDS(s2, d2);
                GLDS(s2 + 4096, d2 + 1024);
                asm volatile("s_waitcnt vmcnt(2)" ::: "memory");   // c+1 complete
            } else {
                asm volatile("s_waitcnt vmcnt(0)" ::: "memory");
            }
            __builtin_amdgcn_s_barrier();
            asm volatile("" ::: "memory");
            // read-ahead frags of chunk c+1 (buf (kc+1)&3) into the opposite set,
            // then MFMA on chunk c's frags (read last phase) — LDS hides under MFMA.
            const char* nb = smem + ((kc + 1) & 3) * 16384;
            if (kc & 1) {   // current = set1, next -> set0
                if (c + 1 < NCH) {
                    #pragma unroll
                    for (int ks = 0; ks < 4; ++ks) {
                        sh0[ks] = *reinterpret_cast<const half8*>(nb + addrH[ks]);
                        sl0[ks] = *reinterpret_cast<const half8*>(nb + addrL[ks]);
                    }
                }
                __builtin_amdgcn_s_setprio(1);
                #pragma unroll
                for (int ks = 0; ks < 4; ++ks) {
                    const int ksg = kc * 4 + ks;
                    accA = MFMA(a_hi[ksg], sh1[ks], accA);
                    accB = MFMA(a_hi[ksg], sl1[ks], accB);
                    accB = MFMA(a_lo[ksg], sh1[ks], accB);
                }
                __builtin_amdgcn_s_setprio(0);
            } else {        // current = set0, next -> set1
                if (c + 1 < NCH) {
                    #pragma unroll
                    for (int ks = 0; ks < 4; ++ks) {
                        sh1[ks] = *reinterpret_cast<const half8*>(nb + addrH[ks]);
                        sl1[ks] = *reinterpret_cast<const half8*>(nb + addrL[ks]);
                    }
                }
                __builtin_amdgcn_s_setprio(1);
                #pragma unroll
                for (int ks = 0; ks < 4; ++ks) {
                    const int ksg = kc * 4 + ks;
                    accA = MFMA(a_hi[ksg], sh0[ks], accA);
                    accB = MFMA(a_hi[ksg], sl0[ks], accB);
                    accB = MFMA(a_lo[ksg], sh0[ks], accB);
                }
                __builtin_amdgcn_s_setprio(0);
            }
        }
        // argmin update: lane col = ni*64 + nw*32 + ll; ascending ni + strict < = first occurrence
        const float e = esq_s[ni * 64 + nw * 32 + ll];
        #pragma unroll
        for (int q = 0; q < 16; ++q) {
            const float v = fmaf(-2.f, accA[q], fmaf(-2.f, accB[q], e));
            const int sh = (q & 3) * 8;
            if (v < rbv[q]) {
                rbv[q] = v;
                rbn[q >> 2] = (rbn[q >> 2] & ~(255u << sh)) | ((unsigned)ni << sh);
            }
        }
    }

    // final per-row argmin: unpack ni -> col, lexicographic shfl reduce over the 32-lane half
    int2* comb = reinterpret_cast<int2*>(smem + 81920);   // [128 rows][2 nw]
    #pragma unroll
    for (int q = 0; q < 16; ++q) {
        float v = rbv[q];
        int i = (int)((rbn[q >> 2] >> ((q & 3) * 8)) & 255u) * 64 + nw * 32 + ll;
        #pragma unroll
        for (int off = 1; off < 32; off <<= 1) {
            float ov = __shfl_xor(v, off);
            int oi = __shfl_xor(i, off);
            if (ov < v || (ov == v && oi < i)) { v = ov; i = oi; }
        }
        if (ll == 0) {   // m74 C-layout: row = (q&3) + 8*(q>>2) + 4*lh
            const int r32 = (q & 3) + 8 * (q >> 2) + 4 * lh;
            comb[(mw * 32 + r32) * 2 + nw] = make_int2(__float_as_int(v), i);
        }
    }
    __syncthreads();
    int* idxF = reinterpret_cast<int*>(smem + 83968);
    if (tid < 128) {
        int2 c0 = comb[tid * 2], c1 = comb[tid * 2 + 1];
        float v0 = __int_as_float(c0.x), v1 = __int_as_float(c1.x);
        idxF[tid] = (v1 < v0 || (v1 == v0 && c1.y < c0.y)) ? c1.y : c0.y;
    }
    __syncthreads();

    // gather: out0 = z + (q - z) (ref's exact fp32 expr), out1 = q, out2 = idx
    {
        const int r = tid >> 2, p4 = tid & 3;
        const int gRow = blkRow + r;
        const int idx = idxF[r];
        const float* wr = w + (size_t)idx * Dn + p4 * 64;
        const float* zr = z + (size_t)gRow * Dn + p4 * 64;
        float* o0 = out0 + (size_t)gRow * Dn + p4 * 64;
        float* o1 = out1 + (size_t)gRow * Dn + p4 * 64;
        #pragma unroll
        for (int q = 0; q < 16; ++q) {
            float4 wq = *reinterpret_cast<const float4*>(wr + q * 4);
            float4 zq = *reinterpret_cast<const float4*>(zr + q * 4);
            *reinterpret_cast<float4*>(o1 + q * 4) = wq;
            float4 sg;
            sg.x = zq.x + (wq.x - zq.x);
            sg.y = zq.y + (wq.y - zq.y);
            sg.z = zq.z + (wq.z - zq.z);
            sg.w = zq.w + (wq.w - zq.w);
            *reinterpret_cast<float4*>(o0 + q * 4) = sg;
        }
        if (p4 == 0) out2[gRow] = (float)idx;
    }
}

extern "C" void kernel_launch(void* const* d_in, const int* in_sizes, int n_in,
                              void* d_out, int out_size, void* d_ws, size_t ws_size,
                              hipStream_t stream) {
    (void)in_sizes; (void)n_in; (void)out_size; (void)ws_size;
    const float* z = (const float*)d_in[0];
    const float* w = (const float*)d_in[1];
    float* esq = (float*)d_ws;                        // 16 KB
    char* w16 = (char*)d_ws + 16384;                  // 4 MB swizzle-baked hi|lo codebook
    float* out0 = (float*)d_out;
    float* out1 = out0 + (size_t)Bn * Dn;
    float* out2 = out1 + (size_t)Bn * Dn;

    prep_kernel<<<Kn / 4, 256, 0, stream>>>(w, esq, w16);
    vq_kernel<<<Bn / BM, 512, 0, stream>>>(z, w, esq, w16, out0, out1, out2);
}